// Round 1
// baseline (4673.880 us; speedup 1.0000x reference)
//
#include <hip/hip_runtime.h>

#define BB 8192
#define TT 64
#define AST 36      // acts row stride (floats): [256 k][36]
#define GST 132     // per-gate padded stride: 128 + 4
#define LSTM_LDS_FLOATS (256*AST + 32*4*GST + 16*4*GST + 640 + 512)
#define LSTM_LDS_BYTES  (LSTM_LDS_FLOATS * 4)

__device__ __forceinline__ float sigf(float x)   { return 1.f / (1.f + __expf(-x)); }
__device__ __forceinline__ float tanh_f(float x) { return 1.f - 2.f / (__expf(2.f * x) + 1.f); }

// ---- 1. weight transpose/combine: Wc[k][col], col = gate*128+j; bc = b_ih+b_hh ----
__global__ void prep_kernel(const float* __restrict__ Wih, const float* __restrict__ Whh,
                            const float* __restrict__ bih, const float* __restrict__ bhh,
                            float* __restrict__ Wc, float* __restrict__ bc) {
  int idx = blockIdx.x * 256 + threadIdx.x;  // 131072 total
  int k = idx >> 9, col = idx & 511;
  Wc[idx] = (k < 128) ? Wih[col * 128 + k] : Whh[col * 128 + (k - 128)];
  if (idx < 512) bc[idx] = bih[idx] + bhh[idx];
}

// ---- 2. per-t raw input moments over batch: sums of x0,x1,x0^2,x0x1,x1^2 ----
__global__ void stats_kernel(const float* __restrict__ x, float* __restrict__ stats) {
  int t = blockIdx.x, tid = threadIdx.x;
  float s0=0, s1=0, s2=0, s3=0, s4=0;
  for (int b = tid; b < BB; b += 256) {
    const float* p = x + ((size_t)b * TT + t) * 2;
    float x0 = p[0], x1 = p[1];
    s0 += x0; s1 += x1; s2 += x0*x0; s3 += x0*x1; s4 += x1*x1;
  }
  __shared__ float red[4][5];
  int lane = tid & 63, w = tid >> 6;
  #pragma unroll
  for (int off = 32; off > 0; off >>= 1) {
    s0 += __shfl_down(s0, off); s1 += __shfl_down(s1, off);
    s2 += __shfl_down(s2, off); s3 += __shfl_down(s3, off); s4 += __shfl_down(s4, off);
  }
  if (lane == 0) { red[w][0]=s0; red[w][1]=s1; red[w][2]=s2; red[w][3]=s3; red[w][4]=s4; }
  __syncthreads();
  if (tid < 5) stats[t*5 + tid] = red[0][tid] + red[1][tid] + red[2][tid] + red[3][tid];
}

// ---- 3. fold input-BN + embed Linear + per-step embed-BN into A0/A1/C tables ----
__global__ void coef_kernel(const float* __restrict__ stats,
                            const float* __restrict__ Wemb, const float* __restrict__ bemb,
                            const float* __restrict__ ing, const float* __restrict__ inb,
                            const float* __restrict__ eg, const float* __restrict__ eb,
                            float* __restrict__ A0, float* __restrict__ A1, float* __restrict__ Ct) {
  __shared__ float st[64][5];
  __shared__ float glob[4];
  int tid = threadIdx.x;  // 128
  for (int i = tid; i < 320; i += 128) st[i / 5][i % 5] = stats[i];
  __syncthreads();
  if (tid == 0) {
    float S0=0, S1=0, S00=0, S11=0;
    for (int t = 0; t < 64; t++) { S0+=st[t][0]; S1+=st[t][1]; S00+=st[t][2]; S11+=st[t][4]; }
    float inv_n = 1.f / (float)(BB * TT);
    float M0 = S0*inv_n, M1 = S1*inv_n;
    float V0 = S00*inv_n - M0*M0, V1 = S11*inv_n - M1*M1;
    float P0 = rsqrtf(V0 + 1e-5f) * ing[0];
    float P1 = rsqrtf(V1 + 1e-5f) * ing[1];
    glob[0]=P0; glob[1]=P1; glob[2]=inb[0]-M0*P0; glob[3]=inb[1]-M1*P1;
  }
  __syncthreads();
  float P0=glob[0], P1=glob[1], Q0=glob[2], Q1=glob[3];
  int j = tid;
  float w0 = Wemb[j*2], w1 = Wemb[j*2+1];
  float a0 = P0*w0, a1 = P1*w1;
  float cj = Q0*w0 + Q1*w1 + bemb[j];
  float gam = eg[j], bet = eb[j];
  float invB = 1.f / (float)BB;
  for (int t = 0; t < 64; t++) {
    float m0 = st[t][0]*invB, m1 = st[t][1]*invB;
    float v00 = st[t][2]*invB - m0*m0;
    float v01 = st[t][3]*invB - m0*m1;
    float v11 = st[t][4]*invB - m1*m1;
    float mean = a0*m0 + a1*m1 + cj;
    float var  = a0*a0*v00 + 2.f*a0*a1*v01 + a1*a1*v11;
    float G = rsqrtf(var + 1e-5f) * gam;
    A0[t*128 + j] = G * a0;
    A1[t*128 + j] = G * a1;
    Ct[t*128 + j] = G * cj + (bet - mean * G);
  }
}

// ---- 4. recurrence: 256 blocks x 32 rows, h/c in registers, t-loop local ----
__launch_bounds__(256, 1)
__global__ void lstm_kernel(const float* __restrict__ x,
                            const float* __restrict__ A0, const float* __restrict__ A1,
                            const float* __restrict__ Ctab,
                            const float* __restrict__ Wc, const float* __restrict__ bc,
                            const float* __restrict__ Wout, const float* __restrict__ bout,
                            float* __restrict__ outy, float* __restrict__ hout,
                            float* __restrict__ cout) {
  extern __shared__ __align__(16) float sm[];
  float* acts = sm;                    // [256][AST]  k<128: e, k>=128: h
  float* gl   = sm + 256*AST;          // [32 rows][4 gates][GST]
  float* wch  = gl + 32*4*GST;         // [16 kk][4 gates][GST]
  float* wo   = wch + 16*4*GST;        // [5][128]
  float* bcs  = wo + 640;              // [512]

  const int tid  = threadIdx.x;
  const int row0 = blockIdx.x * 32;

  // GEMM role: 4 rows x 16 cols x 1 gate per thread
  const int rg  = tid >> 5;            // 0..7 row-group (4 rows)
  const int gt  = (tid >> 3) & 3;      // gate
  const int jbW = (tid & 7) * 16;      // col base
  // elementwise role: 1 row x 16 cols (all 4 gates)
  const int er  = tid >> 3;            // 0..31
  const int ejb = (tid & 7) * 16;

  for (int i = tid; i < 640; i += 256) wo[i]  = Wout[i];
  for (int i = tid; i < 512; i += 256) bcs[i] = bc[i];

  float h[16], c[16];
  #pragma unroll
  for (int i = 0; i < 16; i++) { h[i] = 0.f; c[i] = 0.f; }

  const float* xrow = x + (size_t)(row0 + er) * (TT * 2);

  // init: e(t=0) and h=0 into acts
  {
    float x0 = xrow[0], x1 = xrow[1];
    #pragma unroll
    for (int q = 0; q < 4; q++) {
      int j = ejb + q * 4;
      float4 a0 = *(const float4*)&A0[j];
      float4 a1 = *(const float4*)&A1[j];
      float4 cc = *(const float4*)&Ctab[j];
      acts[(j+0)*AST + er] = fmaxf(fmaf(a0.x,x0,fmaf(a1.x,x1,cc.x)), 0.f);
      acts[(j+1)*AST + er] = fmaxf(fmaf(a0.y,x0,fmaf(a1.y,x1,cc.y)), 0.f);
      acts[(j+2)*AST + er] = fmaxf(fmaf(a0.z,x0,fmaf(a1.z,x1,cc.z)), 0.f);
      acts[(j+3)*AST + er] = fmaxf(fmaf(a0.w,x0,fmaf(a1.w,x1,cc.w)), 0.f);
      acts[(128+j+0)*AST + er] = 0.f;
      acts[(128+j+1)*AST + er] = 0.f;
      acts[(128+j+2)*AST + er] = 0.f;
      acts[(128+j+3)*AST + er] = 0.f;
    }
  }

  float4 pref[8];
  {
    const float4* src = (const float4*)Wc;
    #pragma unroll
    for (int q = 0; q < 8; q++) pref[q] = src[tid + q*256];
  }

  #pragma unroll 1
  for (int t = 0; t < TT; t++) {
    float acc[4][16];
    #pragma unroll
    for (int rr = 0; rr < 4; rr++)
      #pragma unroll
      for (int jj = 0; jj < 16; jj++) acc[rr][jj] = 0.f;

    #pragma unroll 1
    for (int ch = 0; ch < 16; ch++) {
      __syncthreads();                       // acts ready / prev FMA done with wch
      #pragma unroll
      for (int q = 0; q < 8; q++) {          // regs -> LDS (gate-padded layout)
        int fi  = (tid + q*256) * 4;
        int kk  = fi >> 9;
        int col = fi & 511;
        *(float4*)&wch[(kk*4 + (col >> 7)) * GST + (col & 127)] = pref[q];
      }
      if (ch < 15) {
        const float4* src = (const float4*)(Wc + (size_t)(ch+1) * 8192);
        #pragma unroll
        for (int q = 0; q < 8; q++) pref[q] = src[tid + q*256];
      } else if (t < TT-1) {
        const float4* src = (const float4*)Wc;
        #pragma unroll
        for (int q = 0; q < 8; q++) pref[q] = src[tid + q*256];
      }
      __syncthreads();                       // wch ready

      const float* ab = acts + (ch*16)*AST + rg*4;
      const float* wb = wch + gt*GST + jbW;
      #pragma unroll 4
      for (int kk = 0; kk < 16; kk++) {
        float4 av = *(const float4*)(ab + kk*AST);
        float4 w0 = *(const float4*)(wb + kk*4*GST);
        float4 w1 = *(const float4*)(wb + kk*4*GST + 4);
        float4 w2 = *(const float4*)(wb + kk*4*GST + 8);
        float4 w3 = *(const float4*)(wb + kk*4*GST + 12);
        float a_[4] = {av.x, av.y, av.z, av.w};
        float w_[16] = {w0.x,w0.y,w0.z,w0.w, w1.x,w1.y,w1.z,w1.w,
                        w2.x,w2.y,w2.z,w2.w, w3.x,w3.y,w3.z,w3.w};
        #pragma unroll
        for (int rr = 0; rr < 4; rr++)
          #pragma unroll
          for (int jj = 0; jj < 16; jj++)
            acc[rr][jj] = fmaf(a_[rr], w_[jj], acc[rr][jj]);
      }
    }

    // gates (+bias) -> LDS exchange
    #pragma unroll
    for (int rr = 0; rr < 4; rr++) {
      int row = rg*4 + rr;
      #pragma unroll
      for (int q = 0; q < 4; q++) {
        float4 v;
        v.x = acc[rr][q*4+0] + bcs[gt*128 + jbW + q*4+0];
        v.y = acc[rr][q*4+1] + bcs[gt*128 + jbW + q*4+1];
        v.z = acc[rr][q*4+2] + bcs[gt*128 + jbW + q*4+2];
        v.w = acc[rr][q*4+3] + bcs[gt*128 + jbW + q*4+3];
        *(float4*)&gl[(row*4 + gt)*GST + jbW + q*4] = v;
      }
    }
    __syncthreads();                          // gates ready

    float ga[4][16];
    #pragma unroll
    for (int g = 0; g < 4; g++)
      #pragma unroll
      for (int q = 0; q < 4; q++)
        *(float4*)&ga[g][q*4] = *(const float4*)&gl[(er*4 + g)*GST + ejb + q*4];

    #pragma unroll
    for (int jj = 0; jj < 16; jj++) {
      float ii = sigf(ga[0][jj]);
      float ff = sigf(ga[1][jj]);
      float gv = tanh_f(ga[2][jj]);
      float oo = sigf(ga[3][jj]);
      float cn = fmaf(ff, c[jj], ii * gv);
      c[jj] = cn;
      h[jj] = oo * tanh_f(cn);
    }
    #pragma unroll
    for (int jj = 0; jj < 16; jj++)
      acts[(128 + ejb + jj)*AST + er] = h[jj];

    if (t < TT-1) {                           // e(t+1)
      float x0 = xrow[(t+1)*2], x1 = xrow[(t+1)*2 + 1];
      const float* a0p = A0 + (t+1)*128;
      const float* a1p = A1 + (t+1)*128;
      const float* ccp = Ctab + (t+1)*128;
      #pragma unroll
      for (int q = 0; q < 4; q++) {
        int j = ejb + q*4;
        float4 a0 = *(const float4*)&a0p[j];
        float4 a1 = *(const float4*)&a1p[j];
        float4 cc = *(const float4*)&ccp[j];
        acts[(j+0)*AST + er] = fmaxf(fmaf(a0.x,x0,fmaf(a1.x,x1,cc.x)), 0.f);
        acts[(j+1)*AST + er] = fmaxf(fmaf(a0.y,x0,fmaf(a1.y,x1,cc.y)), 0.f);
        acts[(j+2)*AST + er] = fmaxf(fmaf(a0.z,x0,fmaf(a1.z,x1,cc.z)), 0.f);
        acts[(j+3)*AST + er] = fmaxf(fmaf(a0.w,x0,fmaf(a1.w,x1,cc.w)), 0.f);
      }
    }
    __syncthreads();                          // new h visible for y-projection

    if (tid < 160) {                          // raw y = h_new @ Wout^T + bout
      int r = tid / 5, ko = tid - (tid / 5) * 5;
      const float* hp  = acts + 128*AST + r;
      const float* wop = wo + ko*128;
      float y = bout[ko];
      #pragma unroll 8
      for (int j = 0; j < 128; j++)
        y = fmaf(hp[j*AST], wop[j], y);
      outy[((size_t)(row0 + r) * TT + t) * 5 + ko] = y;
    }
  }

  // final h, c
  #pragma unroll
  for (int q = 0; q < 4; q++) {
    float4 v; v.x=h[q*4+0]; v.y=h[q*4+1]; v.z=h[q*4+2]; v.w=h[q*4+3];
    *(float4*)(hout + (size_t)(row0+er)*128 + ejb + q*4) = v;
    float4 u; u.x=c[q*4+0]; u.y=c[q*4+1]; u.z=c[q*4+2]; u.w=c[q*4+3];
    *(float4*)(cout + (size_t)(row0+er)*128 + ejb + q*4) = u;
  }
}

// ---- 5. per-(t,k) output BN stats over batch ----
__global__ void ostats_kernel(const float* __restrict__ outy, float* __restrict__ ost) {
  int t = blockIdx.x, tid = threadIdx.x;
  float s[5] = {0,0,0,0,0}, s2[5] = {0,0,0,0,0};
  for (int b = tid; b < BB; b += 256) {
    const float* p = outy + ((size_t)b * TT + t) * 5;
    #pragma unroll
    for (int k = 0; k < 5; k++) { float v = p[k]; s[k] += v; s2[k] += v*v; }
  }
  __shared__ float red[4][10];
  int lane = tid & 63, w = tid >> 6;
  #pragma unroll
  for (int off = 32; off > 0; off >>= 1) {
    #pragma unroll
    for (int k = 0; k < 5; k++) {
      s[k]  += __shfl_down(s[k], off);
      s2[k] += __shfl_down(s2[k], off);
    }
  }
  if (lane == 0) {
    #pragma unroll
    for (int k = 0; k < 5; k++) { red[w][k] = s[k]; red[w][5+k] = s2[k]; }
  }
  __syncthreads();
  if (tid < 10) ost[t*10 + tid] = red[0][tid]+red[1][tid]+red[2][tid]+red[3][tid];
}

// ---- 6. normalize outs in place ----
__global__ void onorm_kernel(float* __restrict__ outy, const float* __restrict__ ost,
                             const float* __restrict__ og, const float* __restrict__ ob) {
  const int N = BB*TT*5;
  const float invB = 1.f / (float)BB;
  for (int i = blockIdx.x * 256 + threadIdx.x; i < N; i += gridDim.x * 256) {
    int k = i % 5;
    int t = (i / 5) % TT;
    float m = ost[t*10 + k] * invB;
    float v = ost[t*10 + 5 + k] * invB - m*m;
    outy[i] = (outy[i] - m) * rsqrtf(v + 1e-5f) * og[k] + ob[k];
  }
}

extern "C" void kernel_launch(void* const* d_in, const int* in_sizes, int n_in,
                              void* d_out, int out_size, void* d_ws, size_t ws_size,
                              hipStream_t stream) {
  const float* xin  = (const float*)d_in[0];
  const float* ing  = (const float*)d_in[1];
  const float* inb  = (const float*)d_in[2];
  const float* Wemb = (const float*)d_in[3];
  const float* bemb = (const float*)d_in[4];
  const float* eg   = (const float*)d_in[5];
  const float* eb   = (const float*)d_in[6];
  const float* Wih  = (const float*)d_in[7];
  const float* Whh  = (const float*)d_in[8];
  const float* bih  = (const float*)d_in[9];
  const float* bhh  = (const float*)d_in[10];
  const float* Wout = (const float*)d_in[11];
  const float* bout = (const float*)d_in[12];
  const float* og   = (const float*)d_in[13];
  const float* ob   = (const float*)d_in[14];

  float* ws    = (float*)d_ws;
  float* stats = ws;            // 320
  float* A0    = ws + 1024;     // 8192
  float* A1    = ws + 9216;     // 8192
  float* Ct    = ws + 17408;    // 8192
  float* bc    = ws + 25600;    // 512
  float* Wc    = ws + 26624;    // 131072
  float* ost   = ws + 157696;   // 640

  float* outy = (float*)d_out;
  float* hout = outy + (size_t)BB * TT * 5;
  float* cout = hout + (size_t)BB * 128;

  hipFuncSetAttribute((const void*)lstm_kernel,
                      hipFuncAttributeMaxDynamicSharedMemorySize, LSTM_LDS_BYTES);

  prep_kernel <<<512, 256, 0, stream>>>(Wih, Whh, bih, bhh, Wc, bc);
  stats_kernel<<<64, 256, 0, stream>>>(xin, stats);
  coef_kernel <<<1, 128, 0, stream>>>(stats, Wemb, bemb, ing, inb, eg, eb, A0, A1, Ct);
  lstm_kernel <<<256, 256, LSTM_LDS_BYTES, stream>>>(xin, A0, A1, Ct, Wc, bc, Wout, bout,
                                                     outy, hout, cout);
  ostats_kernel<<<64, 256, 0, stream>>>(outy, ost);
  onorm_kernel <<<2048, 256, 0, stream>>>(outy, ost, og, ob);
}

// Round 3
// 341.031 us; speedup vs baseline: 13.7052x; 13.7052x over previous
//
#include <hip/hip_runtime.h>

#define BB 8192
#define TT 64

typedef __attribute__((ext_vector_type(8))) short bf16x8;
typedef __attribute__((ext_vector_type(4))) float f32x4;

__device__ __forceinline__ float sigf(float x)   { return 1.f / (1.f + __expf(-x)); }
__device__ __forceinline__ float tanh_f(float x) { return 1.f - 2.f / (__expf(2.f * x) + 1.f); }
__device__ __forceinline__ unsigned short f2bf(float x) {
  unsigned u = __float_as_uint(x);
  u += 0x7FFFu + ((u >> 16) & 1u);          // round-to-nearest-even
  return (unsigned short)(u >> 16);
}
// swizzled LDS index for acts[row][k] (bf16): granule(16B) XOR'd by row&7
__device__ __forceinline__ int aidx(int row, int k) {
  return row * 256 + ((((k >> 3) ^ (row & 7))) << 3) + (k & 7);
}

// ---- 1. weights -> bf16 MFMA-fragment order; bc = b_ih + b_hh ----
// Wcb frag f = kt*32+nt: lane l elem e = Wc[kt*32+(l>>4)*8+e][nt*16+(l&15)]
__global__ void prep_kernel(const float* __restrict__ Wih, const float* __restrict__ Whh,
                            const float* __restrict__ bih, const float* __restrict__ bhh,
                            const float* __restrict__ Wout,
                            short* __restrict__ Wcb, short* __restrict__ Woutb,
                            float* __restrict__ bc) {
  int idx = blockIdx.x * 256 + threadIdx.x;   // 17152 total
  if (idx < 16384) {
    int l = idx & 63, f = idx >> 6;
    int kt = f >> 5, nt = f & 31;
    int k0 = kt * 32 + ((l >> 4) << 3);
    int col = nt * 16 + (l & 15);
    const float* src = (k0 < 128) ? (Wih + col * 128 + k0) : (Whh + col * 128 + (k0 - 128));
    bf16x8 v;
    #pragma unroll
    for (int e = 0; e < 8; e++) v[e] = (short)f2bf(src[e]);
    *(bf16x8*)(Wcb + (size_t)idx * 8) = v;
  } else if (idx < 16640) {
    int i2 = idx - 16384;
    int l = i2 & 63, f = i2 >> 6;              // f = kyt
    int k0 = f * 32 + ((l >> 4) << 3);
    int col = l & 15;
    bf16x8 v;
    #pragma unroll
    for (int e = 0; e < 8; e++)
      v[e] = (col < 5) ? (short)f2bf(Wout[col * 128 + k0 + e]) : (short)0;
    *(bf16x8*)(Woutb + (size_t)i2 * 8) = v;
  } else {
    int i3 = idx - 16640;
    bc[i3] = bih[i3] + bhh[i3];
  }
}

// ---- 2. per-t raw input moments over batch ----
__global__ void stats_kernel(const float* __restrict__ x, float* __restrict__ stats) {
  int t = blockIdx.x, tid = threadIdx.x;
  float s0=0, s1=0, s2=0, s3=0, s4=0;
  for (int b = tid; b < BB; b += 256) {
    const float* p = x + ((size_t)b * TT + t) * 2;
    float x0 = p[0], x1 = p[1];
    s0 += x0; s1 += x1; s2 += x0*x0; s3 += x0*x1; s4 += x1*x1;
  }
  __shared__ float red[4][5];
  int lane = tid & 63, w = tid >> 6;
  #pragma unroll
  for (int off = 32; off > 0; off >>= 1) {
    s0 += __shfl_down(s0, off); s1 += __shfl_down(s1, off);
    s2 += __shfl_down(s2, off); s3 += __shfl_down(s3, off); s4 += __shfl_down(s4, off);
  }
  if (lane == 0) { red[w][0]=s0; red[w][1]=s1; red[w][2]=s2; red[w][3]=s3; red[w][4]=s4; }
  __syncthreads();
  if (tid < 5) stats[t*5 + tid] = red[0][tid] + red[1][tid] + red[2][tid] + red[3][tid];
}

// ---- 3. fold input-BN + embed Linear + per-step embed-BN into A0/A1/C ----
__global__ void coef_kernel(const float* __restrict__ stats,
                            const float* __restrict__ Wemb, const float* __restrict__ bemb,
                            const float* __restrict__ ing, const float* __restrict__ inb,
                            const float* __restrict__ eg, const float* __restrict__ eb,
                            float* __restrict__ A0, float* __restrict__ A1, float* __restrict__ Ct) {
  __shared__ float st[64][5];
  __shared__ float glob[4];
  int tid = threadIdx.x;  // 128
  for (int i = tid; i < 320; i += 128) st[i / 5][i % 5] = stats[i];
  __syncthreads();
  if (tid == 0) {
    float S0=0, S1=0, S00=0, S11=0;
    for (int t = 0; t < 64; t++) { S0+=st[t][0]; S1+=st[t][1]; S00+=st[t][2]; S11+=st[t][4]; }
    float inv_n = 1.f / (float)(BB * TT);
    float M0 = S0*inv_n, M1 = S1*inv_n;
    float V0 = S00*inv_n - M0*M0, V1 = S11*inv_n - M1*M1;
    float P0 = rsqrtf(V0 + 1e-5f) * ing[0];
    float P1 = rsqrtf(V1 + 1e-5f) * ing[1];
    glob[0]=P0; glob[1]=P1; glob[2]=inb[0]-M0*P0; glob[3]=inb[1]-M1*P1;
  }
  __syncthreads();
  float P0=glob[0], P1=glob[1], Q0=glob[2], Q1=glob[3];
  int j = tid;
  float w0 = Wemb[j*2], w1 = Wemb[j*2+1];
  float a0 = P0*w0, a1 = P1*w1;
  float cj = Q0*w0 + Q1*w1 + bemb[j];
  float gam = eg[j], bet = eb[j];
  float invB = 1.f / (float)BB;
  for (int t = 0; t < 64; t++) {
    float m0 = st[t][0]*invB, m1 = st[t][1]*invB;
    float v00 = st[t][2]*invB - m0*m0;
    float v01 = st[t][3]*invB - m0*m1;
    float v11 = st[t][4]*invB - m1*m1;
    float mean = a0*m0 + a1*m1 + cj;
    float var  = a0*a0*v00 + 2.f*a0*a1*v01 + a1*a1*v11;
    float G = rsqrtf(var + 1e-5f) * gam;
    A0[t*128 + j] = G * a0;
    A1[t*128 + j] = G * a1;
    Ct[t*128 + j] = G * cj + (bet - mean * G);
  }
}

__device__ __forceinline__ void write_e(short* acts_s,
                                        const float* __restrict__ A0, const float* __restrict__ A1,
                                        const float* __restrict__ Ct,
                                        int t, int er, int cg, float x0, float x1) {
  const float4 a0a = *(const float4*)(A0 + t*128 + cg*8);
  const float4 a0b = *(const float4*)(A0 + t*128 + cg*8 + 4);
  const float4 a1a = *(const float4*)(A1 + t*128 + cg*8);
  const float4 a1b = *(const float4*)(A1 + t*128 + cg*8 + 4);
  const float4 cta = *(const float4*)(Ct + t*128 + cg*8);
  const float4 ctb = *(const float4*)(Ct + t*128 + cg*8 + 4);
  float ev[8];
  ev[0] = fmaxf(fmaf(a0a.x, x0, fmaf(a1a.x, x1, cta.x)), 0.f);
  ev[1] = fmaxf(fmaf(a0a.y, x0, fmaf(a1a.y, x1, cta.y)), 0.f);
  ev[2] = fmaxf(fmaf(a0a.z, x0, fmaf(a1a.z, x1, cta.z)), 0.f);
  ev[3] = fmaxf(fmaf(a0a.w, x0, fmaf(a1a.w, x1, cta.w)), 0.f);
  ev[4] = fmaxf(fmaf(a0b.x, x0, fmaf(a1b.x, x1, ctb.x)), 0.f);
  ev[5] = fmaxf(fmaf(a0b.y, x0, fmaf(a1b.y, x1, ctb.y)), 0.f);
  ev[6] = fmaxf(fmaf(a0b.z, x0, fmaf(a1b.z, x1, ctb.z)), 0.f);
  ev[7] = fmaxf(fmaf(a0b.w, x0, fmaf(a1b.w, x1, ctb.w)), 0.f);
  bf16x8 v;
  #pragma unroll
  for (int e = 0; e < 8; e++) v[e] = (short)f2bf(ev[e]);
  *(bf16x8*)&acts_s[er*256 + ((cg ^ (er & 7)) << 3)] = v;
}

// ---- 4. MFMA recurrence: 256 blocks x 32 rows, 8 waves ----
__launch_bounds__(512, 2)
__global__ void lstm_kernel(const float* __restrict__ x,
                            const float* __restrict__ A0, const float* __restrict__ A1,
                            const float* __restrict__ Ctab,
                            const short* __restrict__ Wcb, const float* __restrict__ bc,
                            const short* __restrict__ Woutb, const float* __restrict__ bout,
                            float* __restrict__ outy, float* __restrict__ hout,
                            float* __restrict__ cout) {
  __shared__ __align__(16) short acts_s[32 * 256];  // [row][k] swizzled; k<128 e, k>=128 h
  __shared__ __align__(16) float xs[32 * 128];      // [row][t*2+{0,1}]

  const int tid  = threadIdx.x;
  const int lane = tid & 63;
  const int w    = tid >> 6;        // wave 0..7 -> col slice w*16 of each gate
  const int row0 = blockIdx.x * 32;
  const int cl   = lane & 15;       // col within slice / C-tile col
  const int lq   = lane >> 4;       // lane quad
  const int er   = tid >> 4;        // e-writer row 0..31
  const int cg   = tid & 15;        // e-writer col granule

  // preload x for this block's 32 rows
  {
    const float4* src = (const float4*)(x + (size_t)row0 * 128);
    float4* dst = (float4*)xs;
    dst[tid]       = src[tid];
    dst[tid + 512] = src[tid + 512];
  }

  const float bi_ = bc[0 * 128 + w * 16 + cl];
  const float bf_ = bc[1 * 128 + w * 16 + cl];
  const float bg_ = bc[2 * 128 + w * 16 + cl];
  const float bo_ = bc[3 * 128 + w * 16 + cl];
  const float bov = (cl < 5) ? bout[cl] : 0.f;

  bf16x8 wof[4];
  if ((w & 3) == 0) {               // waves 0 and 4 run the y-projection
    #pragma unroll
    for (int kyt = 0; kyt < 4; kyt++)
      wof[kyt] = *(const bf16x8*)(Woutb + (size_t)(kyt * 64 + lane) * 8);
  }

  __syncthreads();  // xs ready

  // init acts: e(0), h = 0
  write_e(acts_s, A0, A1, Ctab, 0, er, cg, xs[er * 128], xs[er * 128 + 1]);
  {
    bf16x8 z = (bf16x8)0;
    *(bf16x8*)&acts_s[er * 256 + (((16 + cg) ^ (er & 7)) << 3)] = z;
  }
  __syncthreads();

  f32x4 cstate[2] = {{0.f,0.f,0.f,0.f},{0.f,0.f,0.f,0.f}};
  float hl[2][4];

  const bf16x8* wptr = (const bf16x8*)Wcb;

  #pragma unroll 1
  for (int t = 0; t < TT; t++) {
    // A-fragments (e(t), h(t-1)) from swizzled LDS
    bf16x8 af[2][8];
    #pragma unroll
    for (int kt = 0; kt < 8; kt++) {
      #pragma unroll
      for (int mt = 0; mt < 2; mt++) {
        int row = mt * 16 + cl;
        int kg  = kt * 4 + lq;
        af[mt][kt] = *(const bf16x8*)&acts_s[row * 256 + ((kg ^ (row & 7)) << 3)];
      }
    }

    f32x4 acc[4][2];
    #pragma unroll
    for (int g = 0; g < 4; g++)
      #pragma unroll
      for (int mt = 0; mt < 2; mt++) acc[g][mt] = (f32x4){0.f,0.f,0.f,0.f};

    bf16x8 bb[4][4];  // [buf][gate]
    #pragma unroll
    for (int kt = 0; kt < 3; kt++)
      #pragma unroll
      for (int g = 0; g < 4; g++)
        bb[kt][g] = wptr[(kt * 32 + g * 8 + w) * 64 + lane];

    #pragma unroll
    for (int kt = 0; kt < 8; kt++) {
      if (kt < 5) {
        #pragma unroll
        for (int g = 0; g < 4; g++)
          bb[(kt + 3) & 3][g] = wptr[((kt + 3) * 32 + g * 8 + w) * 64 + lane];
      }
      #pragma unroll
      for (int g = 0; g < 4; g++) {
        acc[g][0] = __builtin_amdgcn_mfma_f32_16x16x32_bf16(af[0][kt], bb[kt & 3][g], acc[g][0], 0, 0, 0);
        acc[g][1] = __builtin_amdgcn_mfma_f32_16x16x32_bf16(af[1][kt], bb[kt & 3][g], acc[g][1], 0, 0, 0);
      }
    }

    __syncthreads();  // all acts reads done

    // elementwise LSTM update (lane-local), write h(t) bf16 to LDS
    #pragma unroll
    for (int mt = 0; mt < 2; mt++) {
      #pragma unroll
      for (int q = 0; q < 4; q++) {
        float iv = sigf(acc[0][mt][q] + bi_);
        float fv = sigf(acc[1][mt][q] + bf_);
        float gv = tanh_f(acc[2][mt][q] + bg_);
        float ov = sigf(acc[3][mt][q] + bo_);
        float cn = fmaf(fv, cstate[mt][q], iv * gv);
        cstate[mt][q] = cn;
        float hn = ov * tanh_f(cn);
        hl[mt][q] = hn;
        int row = mt * 16 + lq * 4 + q;
        int k   = 128 + w * 16 + cl;
        acts_s[aidx(row, k)] = (short)f2bf(hn);
      }
    }
    // e(t+1)
    if (t < TT - 1)
      write_e(acts_s, A0, A1, Ctab, t + 1, er, cg,
              xs[er * 128 + (t + 1) * 2], xs[er * 128 + (t + 1) * 2 + 1]);

    __syncthreads();  // writes visible

    // y(t) = h(t) @ Wout^T + bout  (waves 0 and 4; M-tile = w>>2)
    if ((w & 3) == 0) {
      int mty = w >> 2;             // 0 or 1  (32 rows = 2 M-tiles)
      int row = mty * 16 + cl;
      f32x4 ya = (f32x4){0.f,0.f,0.f,0.f};
      #pragma unroll
      for (int kyt = 0; kyt < 4; kyt++) {
        int kg = 16 + kyt * 4 + lq;
        bf16x8 ah = *(const bf16x8*)&acts_s[row * 256 + ((kg ^ (row & 7)) << 3)];
        ya = __builtin_amdgcn_mfma_f32_16x16x32_bf16(ah, wof[kyt], ya, 0, 0, 0);
      }
      if (cl < 5) {
        #pragma unroll
        for (int q = 0; q < 4; q++) {
          int brow = row0 + mty * 16 + lq * 4 + q;
          outy[((size_t)brow * TT + t) * 5 + cl] = ya[q] + bov;
        }
      }
    }
  }

  // final h, c
  #pragma unroll
  for (int mt = 0; mt < 2; mt++) {
    #pragma unroll
    for (int q = 0; q < 4; q++) {
      int brow = row0 + mt * 16 + lq * 4 + q;
      int col  = w * 16 + cl;
      hout[(size_t)brow * 128 + col] = hl[mt][q];
      cout[(size_t)brow * 128 + col] = cstate[mt][q];
    }
  }
}

// ---- 5. per-(t,k) output BN stats ----
__global__ void ostats_kernel(const float* __restrict__ outy, float* __restrict__ ost) {
  int t = blockIdx.x, tid = threadIdx.x;
  float s[5] = {0,0,0,0,0}, s2[5] = {0,0,0,0,0};
  for (int b = tid; b < BB; b += 256) {
    const float* p = outy + ((size_t)b * TT + t) * 5;
    #pragma unroll
    for (int k = 0; k < 5; k++) { float v = p[k]; s[k] += v; s2[k] += v*v; }
  }
  __shared__ float red[4][10];
  int lane = tid & 63, w = tid >> 6;
  #pragma unroll
  for (int off = 32; off > 0; off >>= 1) {
    #pragma unroll
    for (int k = 0; k < 5; k++) {
      s[k]  += __shfl_down(s[k], off);
      s2[k] += __shfl_down(s2[k], off);
    }
  }
  if (lane == 0) {
    #pragma unroll
    for (int k = 0; k < 5; k++) { red[w][k] = s[k]; red[w][5+k] = s2[k]; }
  }
  __syncthreads();
  if (tid < 10) ost[t*10 + tid] = red[0][tid]+red[1][tid]+red[2][tid]+red[3][tid];
}

// ---- 6. normalize outs in place ----
__global__ void onorm_kernel(float* __restrict__ outy, const float* __restrict__ ost,
                             const float* __restrict__ og, const float* __restrict__ ob) {
  const int N = BB*TT*5;
  const float invB = 1.f / (float)BB;
  for (int i = blockIdx.x * 256 + threadIdx.x; i < N; i += gridDim.x * 256) {
    int k = i % 5;
    int t = (i / 5) % TT;
    float m = ost[t*10 + k] * invB;
    float v = ost[t*10 + 5 + k] * invB - m*m;
    outy[i] = (outy[i] - m) * rsqrtf(v + 1e-5f) * og[k] + ob[k];
  }
}

extern "C" void kernel_launch(void* const* d_in, const int* in_sizes, int n_in,
                              void* d_out, int out_size, void* d_ws, size_t ws_size,
                              hipStream_t stream) {
  const float* xin  = (const float*)d_in[0];
  const float* ing  = (const float*)d_in[1];
  const float* inb  = (const float*)d_in[2];
  const float* Wemb = (const float*)d_in[3];
  const float* bemb = (const float*)d_in[4];
  const float* eg   = (const float*)d_in[5];
  const float* eb   = (const float*)d_in[6];
  const float* Wih  = (const float*)d_in[7];
  const float* Whh  = (const float*)d_in[8];
  const float* bih  = (const float*)d_in[9];
  const float* bhh  = (const float*)d_in[10];
  const float* Wout = (const float*)d_in[11];
  const float* bout = (const float*)d_in[12];
  const float* og   = (const float*)d_in[13];
  const float* ob   = (const float*)d_in[14];

  float* ws    = (float*)d_ws;
  float* stats = ws;             // 320
  float* A0    = ws + 1024;      // 8192
  float* A1    = ws + 9216;      // 8192
  float* Ct    = ws + 17408;     // 8192
  float* bc    = ws + 25600;     // 512
  short* Wcb   = (short*)(ws + 26624);   // 131072 shorts (256 KB)
  short* Woutb = (short*)(ws + 92160);   // 2048 shorts (4 KB)
  float* ost   = ws + 93184;     // 640

  float* outy = (float*)d_out;
  float* hout = outy + (size_t)BB * TT * 5;
  float* cout = hout + (size_t)BB * 128;

  prep_kernel <<<67, 256, 0, stream>>>(Wih, Whh, bih, bhh, Wout, Wcb, Woutb, bc);
  stats_kernel<<<64, 256, 0, stream>>>(xin, stats);
  coef_kernel <<<1, 128, 0, stream>>>(stats, Wemb, bemb, ing, inb, eg, eb, A0, A1, Ct);
  lstm_kernel <<<256, 512, 0, stream>>>(xin, A0, A1, Ct, Wcb, bc, Woutb, bout,
                                        outy, hout, cout);
  ostats_kernel<<<64, 256, 0, stream>>>(outy, ost);
  onorm_kernel <<<2048, 256, 0, stream>>>(outy, ost, og, ob);
}

// Round 4
// 248.398 us; speedup vs baseline: 18.8161x; 1.3729x over previous
//
#include <hip/hip_runtime.h>
#include <hip/hip_bf16.h>

#define BB 8192
#define TT 64
#define L2E 1.44269504088896f

typedef __attribute__((ext_vector_type(8))) short bf16x8;
typedef __attribute__((ext_vector_type(4))) float f32x4;

__device__ __forceinline__ float exp2g(float x) { return __builtin_amdgcn_exp2f(x); }
__device__ __forceinline__ float rcpg(float x)  { return __builtin_amdgcn_rcpf(x); }
__device__ __forceinline__ short f2bf_s(float x) {
  __hip_bfloat16 b = __float2bfloat16(x);
  return *reinterpret_cast<short*>(&b);
}
// acts[row][k], k in [0,512): e_buf0, e_buf1, h_buf0, h_buf1. 16B-granule XOR swizzle.
__device__ __forceinline__ int aidx(int row, int k) {
  return row * 512 + ((((k >> 3) ^ (row & 7))) << 3) + (k & 7);
}

// ---- 1. weights -> bf16 MFMA-fragment order, exp2-prescaled; bc = (b_ih+b_hh)*scale ----
// Wcb frag f = kt*32+nt: lane l elem e = scale(gate) * Wc[kt*32+(l>>4)*8+e][nt*16+(l&15)]
__global__ void prep_kernel(const float* __restrict__ Wih, const float* __restrict__ Whh,
                            const float* __restrict__ bih, const float* __restrict__ bhh,
                            const float* __restrict__ Wout,
                            short* __restrict__ Wcb, short* __restrict__ Woutb,
                            float* __restrict__ bc) {
  int idx = blockIdx.x * 256 + threadIdx.x;   // 17152 total
  if (idx < 16384) {
    int l = idx & 63, f = idx >> 6;
    int kt = f >> 5, nt = f & 31;
    int k0 = kt * 32 + ((l >> 4) << 3);
    int col = nt * 16 + (l & 15);
    int gate = col >> 7;
    float s = (gate == 2) ? (2.f * L2E) : (-L2E);
    const float* src = (k0 < 128) ? (Wih + col * 128 + k0) : (Whh + col * 128 + (k0 - 128));
    bf16x8 v;
    #pragma unroll
    for (int e = 0; e < 8; e++) v[e] = f2bf_s(src[e] * s);
    *(bf16x8*)(Wcb + (size_t)idx * 8) = v;
  } else if (idx < 16640) {
    int i2 = idx - 16384;
    int l = i2 & 63, f = i2 >> 6;              // f = kyt
    int k0 = f * 32 + ((l >> 4) << 3);
    int col = l & 15;
    bf16x8 v;
    #pragma unroll
    for (int e = 0; e < 8; e++)
      v[e] = (col < 5) ? f2bf_s(Wout[col * 128 + k0 + e]) : (short)0;
    *(bf16x8*)(Woutb + (size_t)i2 * 8) = v;
  } else {
    int i3 = idx - 16640;
    int gate = i3 >> 7;
    float s = (gate == 2) ? (2.f * L2E) : (-L2E);
    bc[i3] = (bih[i3] + bhh[i3]) * s;
  }
}

// ---- 2. per-t raw input moments over batch ----
__global__ void stats_kernel(const float* __restrict__ x, float* __restrict__ stats) {
  int t = blockIdx.x, tid = threadIdx.x;
  float s0=0, s1=0, s2=0, s3=0, s4=0;
  for (int b = tid; b < BB; b += 256) {
    const float* p = x + ((size_t)b * TT + t) * 2;
    float x0 = p[0], x1 = p[1];
    s0 += x0; s1 += x1; s2 += x0*x0; s3 += x0*x1; s4 += x1*x1;
  }
  __shared__ float red[4][5];
  int lane = tid & 63, w = tid >> 6;
  #pragma unroll
  for (int off = 32; off > 0; off >>= 1) {
    s0 += __shfl_down(s0, off); s1 += __shfl_down(s1, off);
    s2 += __shfl_down(s2, off); s3 += __shfl_down(s3, off); s4 += __shfl_down(s4, off);
  }
  if (lane == 0) { red[w][0]=s0; red[w][1]=s1; red[w][2]=s2; red[w][3]=s3; red[w][4]=s4; }
  __syncthreads();
  if (tid < 5) stats[t*5 + tid] = red[0][tid] + red[1][tid] + red[2][tid] + red[3][tid];
}

// ---- 3. fold input-BN + embed Linear + per-step embed-BN into A0/A1/C ----
__global__ void coef_kernel(const float* __restrict__ stats,
                            const float* __restrict__ Wemb, const float* __restrict__ bemb,
                            const float* __restrict__ ing, const float* __restrict__ inb,
                            const float* __restrict__ eg, const float* __restrict__ eb,
                            float* __restrict__ A0, float* __restrict__ A1, float* __restrict__ Ct) {
  __shared__ float st[64][5];
  __shared__ float glob[4];
  int tid = threadIdx.x;  // 128
  for (int i = tid; i < 320; i += 128) st[i / 5][i % 5] = stats[i];
  __syncthreads();
  if (tid == 0) {
    float S0=0, S1=0, S00=0, S11=0;
    for (int t = 0; t < 64; t++) { S0+=st[t][0]; S1+=st[t][1]; S00+=st[t][2]; S11+=st[t][4]; }
    float inv_n = 1.f / (float)(BB * TT);
    float M0 = S0*inv_n, M1 = S1*inv_n;
    float V0 = S00*inv_n - M0*M0, V1 = S11*inv_n - M1*M1;
    float P0 = rsqrtf(V0 + 1e-5f) * ing[0];
    float P1 = rsqrtf(V1 + 1e-5f) * ing[1];
    glob[0]=P0; glob[1]=P1; glob[2]=inb[0]-M0*P0; glob[3]=inb[1]-M1*P1;
  }
  __syncthreads();
  float P0=glob[0], P1=glob[1], Q0=glob[2], Q1=glob[3];
  int j = tid;
  float w0 = Wemb[j*2], w1 = Wemb[j*2+1];
  float a0 = P0*w0, a1 = P1*w1;
  float cj = Q0*w0 + Q1*w1 + bemb[j];
  float gam = eg[j], bet = eb[j];
  float invB = 1.f / (float)BB;
  for (int t = 0; t < 64; t++) {
    float m0 = st[t][0]*invB, m1 = st[t][1]*invB;
    float v00 = st[t][2]*invB - m0*m0;
    float v01 = st[t][3]*invB - m0*m1;
    float v11 = st[t][4]*invB - m1*m1;
    float mean = a0*m0 + a1*m1 + cj;
    float var  = a0*a0*v00 + 2.f*a0*a1*v01 + a1*a1*v11;
    float G = rsqrtf(var + 1e-5f) * gam;
    A0[t*128 + j] = G * a0;
    A1[t*128 + j] = G * a1;
    Ct[t*128 + j] = G * cj + (bet - mean * G);
  }
}

// write e(t) for row er, granule cg, into e-buffer (t&1)
__device__ __forceinline__ void write_e(short* acts_s,
                                        const float* __restrict__ A0, const float* __restrict__ A1,
                                        const float* __restrict__ Ct,
                                        int t, int er, int cg, float x0, float x1) {
  const float4 a0a = *(const float4*)(A0 + t*128 + cg*8);
  const float4 a0b = *(const float4*)(A0 + t*128 + cg*8 + 4);
  const float4 a1a = *(const float4*)(A1 + t*128 + cg*8);
  const float4 a1b = *(const float4*)(A1 + t*128 + cg*8 + 4);
  const float4 cta = *(const float4*)(Ct + t*128 + cg*8);
  const float4 ctb = *(const float4*)(Ct + t*128 + cg*8 + 4);
  bf16x8 v;
  v[0] = f2bf_s(fmaxf(fmaf(a0a.x, x0, fmaf(a1a.x, x1, cta.x)), 0.f));
  v[1] = f2bf_s(fmaxf(fmaf(a0a.y, x0, fmaf(a1a.y, x1, cta.y)), 0.f));
  v[2] = f2bf_s(fmaxf(fmaf(a0a.z, x0, fmaf(a1a.z, x1, cta.z)), 0.f));
  v[3] = f2bf_s(fmaxf(fmaf(a0a.w, x0, fmaf(a1a.w, x1, cta.w)), 0.f));
  v[4] = f2bf_s(fmaxf(fmaf(a0b.x, x0, fmaf(a1b.x, x1, ctb.x)), 0.f));
  v[5] = f2bf_s(fmaxf(fmaf(a0b.y, x0, fmaf(a1b.y, x1, ctb.y)), 0.f));
  v[6] = f2bf_s(fmaxf(fmaf(a0b.z, x0, fmaf(a1b.z, x1, ctb.z)), 0.f));
  v[7] = f2bf_s(fmaxf(fmaf(a0b.w, x0, fmaf(a1b.w, x1, ctb.w)), 0.f));
  int gk = (t & 1) * 16 + cg;
  *(bf16x8*)&acts_s[er * 512 + ((gk ^ (er & 7)) << 3)] = v;
}

// ---- 4. MFMA recurrence: 256 blocks x 32 rows, 8 waves, weights in VGPRs ----
__launch_bounds__(512, 1)
__global__ void lstm_kernel(const float* __restrict__ x,
                            const float* __restrict__ A0, const float* __restrict__ A1,
                            const float* __restrict__ Ctab,
                            const short* __restrict__ Wcb, const float* __restrict__ bc,
                            const short* __restrict__ Woutb, const float* __restrict__ bout,
                            float* __restrict__ outy, float* __restrict__ hout,
                            float* __restrict__ cout) {
  __shared__ __align__(16) short acts_s[32 * 512];  // [row][k] swizzled, double-buffered e,h
  __shared__ __align__(16) float xs[32 * 128];      // [row][t*2+{0,1}]

  const int tid  = threadIdx.x;
  const int lane = tid & 63;
  const int w    = tid >> 6;        // wave 0..7 -> col slice w*16 of each gate
  const int row0 = blockIdx.x * 32;
  const int cl   = lane & 15;       // col within slice / C-tile col / A-frag row
  const int lq   = lane >> 4;       // lane quad
  const int er   = tid >> 4;        // e-writer row 0..31
  const int cg   = tid & 15;        // e-writer col granule

  // preload x for this block's 32 rows
  {
    const float4* src = (const float4*)(x + (size_t)row0 * 128);
    float4* dst = (float4*)xs;
    dst[tid]       = src[tid];
    dst[tid + 512] = src[tid + 512];
  }

  // per-gate scaled biases (acc init values)
  float bgs[4];
  #pragma unroll
  for (int g = 0; g < 4; g++) bgs[g] = bc[g * 128 + w * 16 + cl];
  const float bov = (cl < 5) ? bout[cl] : 0.f;

  // gate weights resident in VGPRs: 32 fragments = 128 VGPRs
  bf16x8 wreg[8][4];
  {
    const bf16x8* wptr = (const bf16x8*)Wcb;
    #pragma unroll
    for (int kt = 0; kt < 8; kt++)
      #pragma unroll
      for (int g = 0; g < 4; g++)
        wreg[kt][g] = wptr[(size_t)(kt * 32 + g * 8 + w) * 64 + lane];
  }
  bf16x8 wof[4];
  if ((w & 3) == 0) {               // waves 0 and 4 run the y-projection
    #pragma unroll
    for (int kyt = 0; kyt < 4; kyt++)
      wof[kyt] = *(const bf16x8*)(Woutb + (size_t)(kyt * 64 + lane) * 8);
  }

  __syncthreads();  // xs ready

  // init: e(0) -> e-buf 0; h(-1)=0 -> h-buf 1
  write_e(acts_s, A0, A1, Ctab, 0, er, cg, xs[er * 128], xs[er * 128 + 1]);
  {
    bf16x8 z = (bf16x8)0;
    int gk = 32 + 16 + cg;          // h-buf 1
    *(bf16x8*)&acts_s[er * 512 + ((gk ^ (er & 7)) << 3)] = z;
  }

  f32x4 cstate[2] = {{0.f,0.f,0.f,0.f},{0.f,0.f,0.f,0.f}};
  float hl[2][4];

  #pragma unroll 1
  for (int t = 0; t < TT; t++) {
    __syncthreads();                 // step t-1 writes visible; all t-1 reads done
    const int ebuf = t & 1;          // e(t)
    const int hbuf = (t + 1) & 1;    // h(t-1)

    // y(t-1) = h(t-1) @ Wout^T + bout  (waves 0,4)
    if ((w & 3) == 0 && t > 0) {
      int mty = w >> 2;
      int row = mty * 16 + cl;
      f32x4 ya = (f32x4){0.f,0.f,0.f,0.f};
      #pragma unroll
      for (int kyt = 0; kyt < 4; kyt++) {
        int k = 256 + hbuf * 128 + (kyt * 4 + lq) * 8;
        bf16x8 ah = *(const bf16x8*)&acts_s[aidx(row, k)];
        ya = __builtin_amdgcn_mfma_f32_16x16x32_bf16(ah, wof[kyt], ya, 0, 0, 0);
      }
      if (cl < 5) {
        #pragma unroll
        for (int q = 0; q < 4; q++) {
          int brow = row0 + mty * 16 + lq * 4 + q;
          outy[((size_t)brow * TT + (t - 1)) * 5 + cl] = ya[q] + bov;
        }
      }
    }

    // gates = [e(t) | h(t-1)] @ Wc  (B-fragments from registers)
    f32x4 acc[4][2];
    #pragma unroll
    for (int g = 0; g < 4; g++)
      #pragma unroll
      for (int mt = 0; mt < 2; mt++)
        acc[g][mt] = (f32x4){bgs[g], bgs[g], bgs[g], bgs[g]};

    #pragma unroll
    for (int kt = 0; kt < 8; kt++) {
      int k = (kt < 4) ? (ebuf * 128 + (kt * 4 + lq) * 8)
                       : (256 + hbuf * 128 + ((kt - 4) * 4 + lq) * 8);
      bf16x8 a0 = *(const bf16x8*)&acts_s[aidx(cl, k)];
      bf16x8 a1 = *(const bf16x8*)&acts_s[aidx(16 + cl, k)];
      #pragma unroll
      for (int g = 0; g < 4; g++) {
        acc[g][0] = __builtin_amdgcn_mfma_f32_16x16x32_bf16(a0, wreg[kt][g], acc[g][0], 0, 0, 0);
        acc[g][1] = __builtin_amdgcn_mfma_f32_16x16x32_bf16(a1, wreg[kt][g], acc[g][1], 0, 0, 0);
      }
    }

    // elementwise LSTM update (lane-local, exp2-prescaled gates), h(t) -> h-buf t&1
    #pragma unroll
    for (int mt = 0; mt < 2; mt++) {
      #pragma unroll
      for (int q = 0; q < 4; q++) {
        float Ei = exp2g(acc[0][mt][q]);          // e^{-i}
        float Ef = exp2g(acc[1][mt][q]);          // e^{-f}
        float Eg = exp2g(acc[2][mt][q]);          // e^{2g}
        float Eo = exp2g(acc[3][mt][q]);          // e^{-o}
        float di = 1.f + Ei, dg = 1.f + Eg;
        float ig = (Eg - 1.f) * rcpg(di * dg);    // sig(i)*tanh(g)
        float fv = rcpg(1.f + Ef);                // sig(f)
        float cn = fmaf(fv, cstate[mt][q], ig);
        cstate[mt][q] = cn;
        float Ec = exp2g(cn * (2.f * L2E));       // e^{2c}
        float hn = (Ec - 1.f) * rcpg((1.f + Eo) * (1.f + Ec));  // sig(o)*tanh(c)
        hl[mt][q] = hn;
        int row = mt * 16 + lq * 4 + q;
        int k   = 256 + (t & 1) * 128 + w * 16 + cl;
        acts_s[aidx(row, k)] = f2bf_s(hn);
      }
    }
    // e(t+1) -> e-buf (t+1)&1
    if (t < TT - 1)
      write_e(acts_s, A0, A1, Ctab, t + 1, er, cg,
              xs[er * 128 + (t + 1) * 2], xs[er * 128 + (t + 1) * 2 + 1]);
  }

  __syncthreads();                   // h(TT-1) visible
  if ((w & 3) == 0) {                // final y(TT-1)
    int mty = w >> 2;
    int row = mty * 16 + cl;
    int hbuf = TT & 1 ? 0 : 1;       // h(TT-1) in buf (TT-1)&1
    f32x4 ya = (f32x4){0.f,0.f,0.f,0.f};
    #pragma unroll
    for (int kyt = 0; kyt < 4; kyt++) {
      int k = 256 + ((TT - 1) & 1) * 128 + (kyt * 4 + lq) * 8;
      bf16x8 ah = *(const bf16x8*)&acts_s[aidx(row, k)];
      ya = __builtin_amdgcn_mfma_f32_16x16x32_bf16(ah, wof[kyt], ya, 0, 0, 0);
    }
    (void)hbuf;
    if (cl < 5) {
      #pragma unroll
      for (int q = 0; q < 4; q++) {
        int brow = row0 + mty * 16 + lq * 4 + q;
        outy[((size_t)brow * TT + (TT - 1)) * 5 + cl] = ya[q] + bov;
      }
    }
  }

  // final h, c
  #pragma unroll
  for (int mt = 0; mt < 2; mt++) {
    #pragma unroll
    for (int q = 0; q < 4; q++) {
      int brow = row0 + mt * 16 + lq * 4 + q;
      int col  = w * 16 + cl;
      hout[(size_t)brow * 128 + col] = hl[mt][q];
      cout[(size_t)brow * 128 + col] = cstate[mt][q];
    }
  }
}

// ---- 5. per-(t,k) output BN stats ----
__global__ void ostats_kernel(const float* __restrict__ outy, float* __restrict__ ost) {
  int t = blockIdx.x, tid = threadIdx.x;
  float s[5] = {0,0,0,0,0}, s2[5] = {0,0,0,0,0};
  for (int b = tid; b < BB; b += 256) {
    const float* p = outy + ((size_t)b * TT + t) * 5;
    #pragma unroll
    for (int k = 0; k < 5; k++) { float v = p[k]; s[k] += v; s2[k] += v*v; }
  }
  __shared__ float red[4][10];
  int lane = tid & 63, w = tid >> 6;
  #pragma unroll
  for (int off = 32; off > 0; off >>= 1) {
    #pragma unroll
    for (int k = 0; k < 5; k++) {
      s[k]  += __shfl_down(s[k], off);
      s2[k] += __shfl_down(s2[k], off);
    }
  }
  if (lane == 0) {
    #pragma unroll
    for (int k = 0; k < 5; k++) { red[w][k] = s[k]; red[w][5+k] = s2[k]; }
  }
  __syncthreads();
  if (tid < 10) ost[t*10 + tid] = red[0][tid]+red[1][tid]+red[2][tid]+red[3][tid];
}

// ---- 6. normalize outs in place ----
__global__ void onorm_kernel(float* __restrict__ outy, const float* __restrict__ ost,
                             const float* __restrict__ og, const float* __restrict__ ob) {
  const int N = BB*TT*5;
  const float invB = 1.f / (float)BB;
  for (int i = blockIdx.x * 256 + threadIdx.x; i < N; i += gridDim.x * 256) {
    int k = i % 5;
    int t = (i / 5) % TT;
    float m = ost[t*10 + k] * invB;
    float v = ost[t*10 + 5 + k] * invB - m*m;
    outy[i] = (outy[i] - m) * rsqrtf(v + 1e-5f) * og[k] + ob[k];
  }
}

extern "C" void kernel_launch(void* const* d_in, const int* in_sizes, int n_in,
                              void* d_out, int out_size, void* d_ws, size_t ws_size,
                              hipStream_t stream) {
  const float* xin  = (const float*)d_in[0];
  const float* ing  = (const float*)d_in[1];
  const float* inb  = (const float*)d_in[2];
  const float* Wemb = (const float*)d_in[3];
  const float* bemb = (const float*)d_in[4];
  const float* eg   = (const float*)d_in[5];
  const float* eb   = (const float*)d_in[6];
  const float* Wih  = (const float*)d_in[7];
  const float* Whh  = (const float*)d_in[8];
  const float* bih  = (const float*)d_in[9];
  const float* bhh  = (const float*)d_in[10];
  const float* Wout = (const float*)d_in[11];
  const float* bout = (const float*)d_in[12];
  const float* og   = (const float*)d_in[13];
  const float* ob   = (const float*)d_in[14];

  float* ws    = (float*)d_ws;
  float* stats = ws;             // 320
  float* A0    = ws + 1024;      // 8192
  float* A1    = ws + 9216;      // 8192
  float* Ct    = ws + 17408;     // 8192
  float* bc    = ws + 25600;     // 512
  short* Wcb   = (short*)(ws + 26624);   // 131072 shorts (256 KB)
  short* Woutb = (short*)(ws + 92160);   // 2048 shorts (4 KB)
  float* ost   = ws + 93184;     // 640

  float* outy = (float*)d_out;
  float* hout = outy + (size_t)BB * TT * 5;
  float* cout = hout + (size_t)BB * 128;

  prep_kernel <<<67, 256, 0, stream>>>(Wih, Whh, bih, bhh, Wout, Wcb, Woutb, bc);
  stats_kernel<<<64, 256, 0, stream>>>(xin, stats);
  coef_kernel <<<1, 128, 0, stream>>>(stats, Wemb, bemb, ing, inb, eg, eb, A0, A1, Ct);
  lstm_kernel <<<256, 512, 0, stream>>>(xin, A0, A1, Ct, Wcb, bc, Woutb, bout,
                                        outy, hout, cout);
  ostats_kernel<<<64, 256, 0, stream>>>(outy, ost);
  onorm_kernel <<<2048, 256, 0, stream>>>(outy, ost, og, ob);
}